// Round 4
// baseline (300.979 us; speedup 1.0000x reference)
//
#include <hip/hip_runtime.h>
#include <math.h>

// Problem constants
#define B_ROWS 16384      // 8*2048 batch rows
#define IDIM   1024
#define ODIM   1024
#define NGRID  9          // NUM_SEGMENTS + 1

#define RS_BLOCKS 1024
#define RS_ROWS   (B_ROWS / RS_BLOCKS)   // 16 rows per block

// GEMM grid: BM=128 BN=64 -> 16 n-tiles. 18 groups x 128 = 2304 blocks.
// Swizzle: within a 128-id window, (id&7) selects m-tile class -> the 16
// n-blocks of one m-tile share an XCD (round-robin dispatch) for A-tile L2 reuse.
#define GEMM_GROUPS 18
#define GEMM_BLOCKS (GEMM_GROUPS * 128)

typedef __attribute__((ext_vector_type(8))) short frag8;   // 8 x bf16 (4 VGPRs)
typedef __attribute__((ext_vector_type(4))) float f32x4;   // MFMA accumulator

typedef __attribute__((address_space(1))) void gvoid;
typedef __attribute__((address_space(3))) void lvoid;

__device__ __forceinline__ void async_cp16(const void* g, void* l) {
  // 16B/lane global->LDS DMA; LDS dest = wave-uniform base + lane*16.
  // Global side is a normal per-lane VMEM address (gather OK).
  __builtin_amdgcn_global_load_lds((gvoid*)(void*)g, (lvoid*)l, 16, 0, 0);
}

__device__ __forceinline__ unsigned short f2bf(float f) {
  union { float f; unsigned u; } v; v.f = f;
  unsigned u = v.u;
  u += 0x7fffu + ((u >> 16) & 1u);      // round-to-nearest-even
  return (unsigned short)(u >> 16);
}

// Per-row hat weights: at most 2 nonzero, at segments {s, s+1}
__device__ __forceinline__ void seg_weights(float m, int& sI, float& w0, float& w1) {
  float wsum = 0.f, wg[NGRID];
#pragma unroll
  for (int g = 0; g < NGRID; g++) {
    float gv = -1.f + 0.25f * (float)g;
    float t = 1.f - fabsf(m - gv) * 4.f;   // 1/h = 4
    wg[g] = t > 0.f ? t : 0.f;
    wsum += wg[g];
  }
  int s = (int)floorf((m + 1.f) * 4.f);
  s = s < 0 ? 0 : (s > 7 ? 7 : s);
  float inv = 1.f / (wsum + 1e-8f);
  sI = s;
  w0 = wg[s] * inv;
  w1 = wg[s + 1] * inv;
}

// ---------------- Pass 1 (fused): mean/weights/segment + bf16 cvt + seg lists --
__global__ void row_stats_fused(const float* __restrict__ x,
                                unsigned short* __restrict__ Xb,
                                float2* __restrict__ ws2,
                                int* __restrict__ seg_rows,
                                int* __restrict__ bucket_cnt) {
  __shared__ int lcnt[NGRID];
  __shared__ int base[NGRID];
  __shared__ int lrank[RS_ROWS];
  __shared__ int lseg[RS_ROWS];
  const int tid  = threadIdx.x;          // 256 threads, 4 waves
  const int lane = tid & 63;
  const int wave = tid >> 6;
  if (tid < NGRID) lcnt[tid] = 0;
  __syncthreads();
  const int row0 = blockIdx.x * RS_ROWS;
#pragma unroll
  for (int it = 0; it < RS_ROWS / 4; ++it) {
    int r = it * 4 + wave;               // one wave per row
    int b = row0 + r;
    const float4* xr = (const float4*)(x + (size_t)b * IDIM);
    ushort4* xw = (ushort4*)(Xb + (size_t)b * IDIM);
    float4 v[4];
    float s = 0.f;
#pragma unroll
    for (int j = 0; j < 4; j++) {        // 4 independent 16B loads/lane
      v[j] = xr[lane + j * 64];
      s += v[j].x + v[j].y + v[j].z + v[j].w;
    }
#pragma unroll
    for (int j = 0; j < 4; j++) {        // bf16 copy straight from registers
      ushort4 u;
      u.x = f2bf(v[j].x); u.y = f2bf(v[j].y); u.z = f2bf(v[j].z); u.w = f2bf(v[j].w);
      xw[lane + j * 64] = u;
    }
#pragma unroll
    for (int off = 32; off; off >>= 1) s += __shfl_down(s, off, 64);
    if (lane == 0) {
      float m = s * (1.0f / (float)IDIM);
      int sI; float w0, w1;
      seg_weights(m, sI, w0, w1);
      ws2[b] = make_float2(w0, w1);
      lseg[r] = sI;
      lrank[r] = atomicAdd(&lcnt[sI], 1);   // LDS atomic: cheap
    }
  }
  __syncthreads();
  if (tid < NGRID) base[tid] = lcnt[tid] ? atomicAdd(&bucket_cnt[tid], lcnt[tid]) : 0;
  __syncthreads();
  if (tid < RS_ROWS)
    seg_rows[lseg[tid] * B_ROWS + base[lseg[tid]] + lrank[tid]] = row0 + tid;
}

// ---------------- Pass 2: coeff fp32 -> bf16, only planes actually needed ----
#define CV_BLKS_PER_PLANE (ODIM * IDIM / 4 / 256)   // 1024
__global__ void cvt_coeff(const float* __restrict__ c, unsigned short* __restrict__ cb,
                          const int* __restrict__ bucket_cnt) {
  const int g  = blockIdx.x >> 10;            // plane 0..8
  const int cI = blockIdx.x & 1023;
  bool need = bucket_cnt[g] > 0;
  if (!need && g > 0) need = bucket_cnt[g - 1] > 0;
  if (!need) return;
  int i = (g * CV_BLKS_PER_PLANE + cI) * 256 + threadIdx.x;
  float4 v = ((const float4*)c)[i];
  ushort4 o;
  o.x = f2bf(v.x); o.y = f2bf(v.y); o.z = f2bf(v.z); o.w = f2bf(v.w);
  ((ushort4*)cb)[i] = o;
}

// ---------------- Pass 3: MFMA GEMM, A-in-registers, B via LDS ---------------
// acc0 = X[rows] @ coeff[seg]^T, acc1 = X[rows] @ coeff[seg+1]^T  (K=1024)
// out[row] = w0[row]*acc0 + w1[row]*acc1 + bias.
// Round-0 geometry (BM=128, BN=64 real x 2 planes, 4 waves 2x2), but A never
// touches LDS: the MFMA A-fragment (lane l holds row l&15, k-chunk (l>>4)*8)
// is a clean per-lane 16B gather (16 rows x 64B consecutive) straight from Xb.
// LDS serial cost per block-K-step drops 512 -> 256 cyc (B write 128 + B read
// 128) vs 155 cyc MFMA -> ceiling 60% (round-0 measured exactly its 30.3%
// LDS-model ceiling). A-tile is L2-hot: all 16 n-blocks of an m-tile map to
// one XCD via the swizzle. A-loads issue before the staging barrier so their
// latency overlaps the B-DMA drain.
// B bank-conflict fix (round-0 proven, 0 conflicts): k-chunk XOR swizzle.
__global__ void __launch_bounds__(256, 3)
kan_gemm(const unsigned short* __restrict__ Xb,
         const unsigned short* __restrict__ Cb,
         const int* __restrict__ seg_rows,
         const int* __restrict__ bucket_cnt,
         const float2* __restrict__ ws2,
         const float* __restrict__ bias,
         float* __restrict__ out) {
  // XCD swizzle: sub&7 -> m-tile class (same XCD), sub>>3 -> n-tile (0..15).
  const int sub = blockIdx.x & 127;
  const int mt  = (blockIdx.x >> 7) * 8 + (sub & 7);
  const int nt  = sub >> 3;

  // Map m-tile -> (segment, local tile, bucket count) from the 9 counters.
  int seg = -1, lt = 0, cnt = 0;
  {
    int t0 = 0;
#pragma unroll
    for (int g = 0; g < NGRID; g++) {
      int c   = bucket_cnt[g];
      int ntg = (c + 127) >> 7;
      if (mt >= t0 && mt < t0 + ntg) { seg = g; lt = mt - t0; cnt = c; }
      t0 += ntg;
    }
  }
  if (seg < 0) return;                      // uniform over block: barrier-safe
  const int rlim = cnt - lt * 128;          // valid rows in this tile (1..128)
  const int* rows = seg_rows + seg * B_ROWS + lt * 128;

  __shared__ unsigned short Bs0[2][64 * 32];   // 8 KB
  __shared__ unsigned short Bs1[2][64 * 32];   // 8 KB

  const int tid  = threadIdx.x;
  const int lane = tid & 63;
  const int wave = tid >> 6;                // 4 waves, 2x2 over 128x64
  const int wm   = wave >> 1;               // 0..1 -> 64-row half
  const int wn   = wave & 1;                // 0..1 -> 32-col half
  const int colB0 = nt * 64;

  const int lrow = lane >> 2;               // 0..15 rows per 1KB issue
  // staging k-offset (shorts): XOR-swizzled chunk of this lane's row
  const int lswz = (((lane & 3) ^ ((lane >> 3) & 3))) * 8;
  // reader k-offset (shorts): un-swizzle for row r=lane&15, chunk q=lane>>4
  const int rswz = (((lane >> 4) ^ ((lane >> 1) & 3))) * 8;

  // Per-lane A gather offsets (shorts): row = wm*64 + mi*16 + (lane&15),
  // k base = (lane>>4)*8. Clamp padding lanes to a valid row (masked later).
  unsigned aoff[4];
#pragma unroll
  for (int mi = 0; mi < 4; mi++) {
    int idx = wm * 64 + mi * 16 + (lane & 15);
    int rid = rows[idx < rlim ? idx : rlim - 1];
    aoff[mi] = (unsigned)rid * IDIM + ((lane >> 4) & 3) * 8;
  }

  // B staging: each wave loads one 16-row group of the 64-row B tiles.
  const unsigned short* gB0 = Cb + ((size_t)(seg * ODIM + colB0 + wave * 16 + lrow)) * IDIM + lswz;
  const unsigned short* gB1 = gB0 + (size_t)ODIM * IDIM;

  f32x4 acc0[4][2] = {};
  f32x4 acc1[4][2] = {};

  for (int kk = 0; kk < IDIM; kk += 64) {
    __syncthreads();                        // prior iter's LDS reads complete
#pragma unroll
    for (int h = 0; h < 2; h++) {
      int ko = kk + h * 32;
      async_cp16(gB0 + ko, &Bs0[h][wave * 16 * 32]);
      async_cp16(gB1 + ko, &Bs1[h][wave * 16 * 32]);
    }
    // A fragments straight from global: issued before the staging barrier so
    // their (L2) latency hides under the B-DMA drain.
    frag8 af[2][4];
#pragma unroll
    for (int h = 0; h < 2; h++)
#pragma unroll
      for (int mi = 0; mi < 4; mi++)
        af[h][mi] = *(const frag8*)(Xb + aoff[mi] + kk + h * 32);
    __syncthreads();                        // staging visible (vmcnt drain at barrier)

#pragma unroll
    for (int h = 0; h < 2; h++) {
      frag8 bfr[2];
#pragma unroll
      for (int ni = 0; ni < 2; ni++)
        bfr[ni] = *(const frag8*)&Bs0[h][(wn * 2 + ni) * 512 + (lane & 15) * 32 + rswz];
#pragma unroll
      for (int mi = 0; mi < 4; mi++)
#pragma unroll
        for (int ni = 0; ni < 2; ni++)
          acc0[mi][ni] = __builtin_amdgcn_mfma_f32_16x16x32_bf16(af[h][mi], bfr[ni], acc0[mi][ni], 0, 0, 0);
#pragma unroll
      for (int ni = 0; ni < 2; ni++)
        bfr[ni] = *(const frag8*)&Bs1[h][(wn * 2 + ni) * 512 + (lane & 15) * 32 + rswz];
#pragma unroll
      for (int mi = 0; mi < 4; mi++)
#pragma unroll
        for (int ni = 0; ni < 2; ni++)
          acc1[mi][ni] = __builtin_amdgcn_mfma_f32_16x16x32_bf16(af[h][mi], bfr[ni], acc1[mi][ni], 0, 0, 0);
    }
  }

  // Epilogue: D col = lane&15, row = (lane>>4)*4 + reg  [m89/m91 verified]
  int   col[2]; float bv[2];
#pragma unroll
  for (int ni = 0; ni < 2; ni++) {
    col[ni] = colB0 + wn * 32 + ni * 16 + (lane & 15);
    bv[ni]  = bias[col[ni]];
  }
#pragma unroll
  for (int mi = 0; mi < 4; mi++) {
    int irow = wm * 64 + mi * 16 + (lane >> 4) * 4;
#pragma unroll
    for (int r = 0; r < 4; r++) {
      int idx = irow + r;
      if (idx < rlim) {                     // non-padding row
        int orow = rows[idx];
        float2 w = ws2[orow];
        float* o = out + (size_t)orow * ODIM;
#pragma unroll
        for (int ni = 0; ni < 2; ni++)
          o[col[ni]] = w.x * acc0[mi][ni][r] + w.y * acc1[mi][ni][r] + bv[ni];
      }
    }
  }
}

// ---------------- Fallback (ws too small): slow fp32, correct ----------------
__global__ void fallback_kernel(const float* __restrict__ x, const float* __restrict__ coeff,
                                const float* __restrict__ bias, float* __restrict__ out) {
  int b = blockIdx.x;
  int tid = threadIdx.x;
  __shared__ float xs[IDIM];
  __shared__ float ps[4];
  __shared__ float mw[2];
  __shared__ int   ms;
  float4 v = ((const float4*)(x + (size_t)b * IDIM))[tid];
  ((float4*)xs)[tid] = v;
  float s = v.x + v.y + v.z + v.w;
#pragma unroll
  for (int off = 32; off; off >>= 1) s += __shfl_down(s, off, 64);
  if ((tid & 63) == 0) ps[tid >> 6] = s;
  __syncthreads();
  if (tid == 0) {
    float m = (ps[0] + ps[1] + ps[2] + ps[3]) * (1.0f / (float)IDIM);
    int sI; float w0, w1;
    seg_weights(m, sI, w0, w1);
    mw[0] = w0; mw[1] = w1; ms = sI;
  }
  __syncthreads();
  float w0 = mw[0], w1 = mw[1]; int sI = ms;
  for (int o = tid; o < ODIM; o += 256) {
    const float* c0 = coeff + ((size_t)sI * ODIM + o) * IDIM;
    const float* c1 = c0 + (size_t)ODIM * IDIM;
    float a0 = 0.f, a1 = 0.f;
    for (int i = 0; i < IDIM; i++) { a0 += xs[i] * c0[i]; a1 += xs[i] * c1[i]; }
    out[(size_t)b * ODIM + o] = w0 * a0 + w1 * a1 + bias[o];
  }
}

extern "C" void kernel_launch(void* const* d_in, const int* in_sizes, int n_in,
                              void* d_out, int out_size, void* d_ws, size_t ws_size,
                              hipStream_t stream) {
  const float* x     = (const float*)d_in[0];
  const float* coeff = (const float*)d_in[1];
  const float* bias  = (const float*)d_in[2];
  float* out = (float*)d_out;

  // Workspace layout (16B-aligned chunks)
  size_t szXb = (size_t)B_ROWS * IDIM * sizeof(unsigned short);       // 33,554,432
  size_t szCb = (size_t)NGRID * ODIM * IDIM * sizeof(unsigned short); // 18,874,368
  size_t o0 = 0;
  unsigned short* Xb = (unsigned short*)((char*)d_ws + o0); o0 += szXb;
  unsigned short* Cb = (unsigned short*)((char*)d_ws + o0); o0 += szCb;
  float2* ws2 = (float2*)((char*)d_ws + o0); o0 += (size_t)B_ROWS * 8;
  int* seg_rows = (int*)((char*)d_ws + o0); o0 += (size_t)NGRID * B_ROWS * 4;
  int* bucket_cnt = (int*)((char*)d_ws + o0); o0 += 256;

  if (ws_size < o0) {
    // Emergency slow path: no workspace required.
    fallback_kernel<<<B_ROWS, 256, 0, stream>>>(x, coeff, bias, out);
    return;
  }

  hipMemsetAsync(bucket_cnt, 0, NGRID * sizeof(int), stream);
  row_stats_fused<<<RS_BLOCKS, 256, 0, stream>>>(x, Xb, ws2, seg_rows, bucket_cnt);
  cvt_coeff<<<NGRID * CV_BLKS_PER_PLANE, 256, 0, stream>>>(coeff, Cb, bucket_cnt);
  kan_gemm<<<GEMM_BLOCKS, 256, 0, stream>>>(Xb, Cb, seg_rows, bucket_cnt, ws2, bias, out);
}

// Round 5
// 234.931 us; speedup vs baseline: 1.2811x; 1.2811x over previous
//
#include <hip/hip_runtime.h>
#include <math.h>

// Problem constants
#define B_ROWS 16384      // 8*2048 batch rows
#define IDIM   1024
#define ODIM   1024
#define NGRID  9          // NUM_SEGMENTS + 1

#define RS_BLOCKS 1024
#define RS_ROWS   (B_ROWS / RS_BLOCKS)   // 16 rows per block

// GEMM grid: BM=128 BN=64 -> 16 n-tiles. 18 groups x 128 = 2304 blocks.
// Swizzle: within a 128-id window, (id&7) selects m-tile class -> the 16
// n-blocks of one m-tile share an XCD (round-robin dispatch) for A-tile L2 reuse.
#define GEMM_GROUPS 18
#define GEMM_BLOCKS (GEMM_GROUPS * 128)

typedef __attribute__((ext_vector_type(8))) short frag8;   // 8 x bf16 (4 VGPRs)
typedef __attribute__((ext_vector_type(4))) float f32x4;   // MFMA accumulator

typedef __attribute__((address_space(1))) void gvoid;
typedef __attribute__((address_space(3))) void lvoid;

__device__ __forceinline__ void async_cp16(const void* g, void* l) {
  // 16B/lane global->LDS DMA; LDS dest = wave-uniform base + lane*16.
  // Global side is a normal per-lane VMEM address (gather OK).
  __builtin_amdgcn_global_load_lds((gvoid*)(void*)g, (lvoid*)l, 16, 0, 0);
}

__device__ __forceinline__ unsigned short f2bf(float f) {
  union { float f; unsigned u; } v; v.f = f;
  unsigned u = v.u;
  u += 0x7fffu + ((u >> 16) & 1u);      // round-to-nearest-even
  return (unsigned short)(u >> 16);
}

// Per-row hat weights: at most 2 nonzero, at segments {s, s+1}
__device__ __forceinline__ void seg_weights(float m, int& sI, float& w0, float& w1) {
  float wsum = 0.f, wg[NGRID];
#pragma unroll
  for (int g = 0; g < NGRID; g++) {
    float gv = -1.f + 0.25f * (float)g;
    float t = 1.f - fabsf(m - gv) * 4.f;   // 1/h = 4
    wg[g] = t > 0.f ? t : 0.f;
    wsum += wg[g];
  }
  int s = (int)floorf((m + 1.f) * 4.f);
  s = s < 0 ? 0 : (s > 7 ? 7 : s);
  float inv = 1.f / (wsum + 1e-8f);
  sI = s;
  w0 = wg[s] * inv;
  w1 = wg[s + 1] * inv;
}

// ---------------- Pass 1 (fused): mean/weights/segment + bf16 cvt + seg lists --
// Each wave handles one row: data stays in registers, so the bf16 copy is
// written with NO re-read. Two-level atomic aggregation for ranks.
// Weights are ALSO stored segment-sorted (ws_s[seg*B_ROWS + rank]) so the
// GEMM epilogue reads them contiguously instead of scattering via row id.
__global__ void row_stats_fused(const float* __restrict__ x,
                                unsigned short* __restrict__ Xb,
                                float2* __restrict__ ws_s,
                                int* __restrict__ seg_rows,
                                int* __restrict__ bucket_cnt) {
  __shared__ int lcnt[NGRID];
  __shared__ int base[NGRID];
  __shared__ int lrank[RS_ROWS];
  __shared__ int lseg[RS_ROWS];
  __shared__ float2 lws[RS_ROWS];
  const int tid  = threadIdx.x;          // 256 threads, 4 waves
  const int lane = tid & 63;
  const int wave = tid >> 6;
  if (tid < NGRID) lcnt[tid] = 0;
  __syncthreads();
  const int row0 = blockIdx.x * RS_ROWS;
#pragma unroll
  for (int it = 0; it < RS_ROWS / 4; ++it) {
    int r = it * 4 + wave;               // one wave per row
    int b = row0 + r;
    const float4* xr = (const float4*)(x + (size_t)b * IDIM);
    ushort4* xw = (ushort4*)(Xb + (size_t)b * IDIM);
    float4 v[4];
    float s = 0.f;
#pragma unroll
    for (int j = 0; j < 4; j++) {        // 4 independent 16B loads/lane
      v[j] = xr[lane + j * 64];
      s += v[j].x + v[j].y + v[j].z + v[j].w;
    }
#pragma unroll
    for (int j = 0; j < 4; j++) {        // bf16 copy straight from registers
      ushort4 u;
      u.x = f2bf(v[j].x); u.y = f2bf(v[j].y); u.z = f2bf(v[j].z); u.w = f2bf(v[j].w);
      xw[lane + j * 64] = u;
    }
#pragma unroll
    for (int off = 32; off; off >>= 1) s += __shfl_down(s, off, 64);
    if (lane == 0) {
      float m = s * (1.0f / (float)IDIM);
      int sI; float w0, w1;
      seg_weights(m, sI, w0, w1);
      lws[r] = make_float2(w0, w1);
      lseg[r] = sI;
      lrank[r] = atomicAdd(&lcnt[sI], 1);   // LDS atomic: cheap
    }
  }
  __syncthreads();
  if (tid < NGRID) base[tid] = lcnt[tid] ? atomicAdd(&bucket_cnt[tid], lcnt[tid]) : 0;
  __syncthreads();
  if (tid < RS_ROWS) {
    int p = lseg[tid] * B_ROWS + base[lseg[tid]] + lrank[tid];
    seg_rows[p] = row0 + tid;
    ws_s[p] = lws[tid];
  }
}

// ---------------- Pass 2: coeff fp32 -> bf16, only planes actually needed ----
// Plane h is needed iff some non-empty bucket g has h in {g, g+1}.
#define CV_BLKS_PER_PLANE (ODIM * IDIM / 4 / 256)   // 1024
__global__ void cvt_coeff(const float* __restrict__ c, unsigned short* __restrict__ cb,
                          const int* __restrict__ bucket_cnt) {
  const int g  = blockIdx.x >> 10;            // plane 0..8
  const int cI = blockIdx.x & 1023;
  bool need = bucket_cnt[g] > 0;
  if (!need && g > 0) need = bucket_cnt[g - 1] > 0;
  if (!need) return;
  int i = (g * CV_BLKS_PER_PLANE + cI) * 256 + threadIdx.x;
  float4 v = ((const float4*)c)[i];
  ushort4 o;
  o.x = f2bf(v.x); o.y = f2bf(v.y); o.z = f2bf(v.z); o.w = f2bf(v.w);
  ((ushort4*)cb)[i] = o;
}

// ---------------- Pass 3: MFMA GEMM, dual-acc, BM=128 BN=64, gather-A --------
// acc0 = X[rows] @ coeff[seg]^T, acc1 = X[rows] @ coeff[seg+1]^T  (K=1024)
// out[row] = w0*acc0 + w1*acc1 + bias.  Round-0 proven schedule (single-buffer
// 2-barrier, ~2.7 blocks/CU of cross-block overlap), with ONE delta:
// 128B-granule staging. Every tile row is stored as 64 shorts (128B); one
// DMA issue covers 8 rows x 128B (vs 16 rows x 64B), halving HBM line fetches
// for the gathered A rows. Swizzle: logical 16B chunk d (0..7) of row r is
// stored at slot d ^ (r&7) (involution). Staging lane l (row l>>3, slot l&7)
// fetches src chunk (l&7)^(l>>3) -- a permutation within the same 128B span,
// so source coalescing per row is a full 128B line. Readers (16-lane phases,
// row r = lane&15, logical chunk h*4+(lane>>4)) hit 8 bank-quads x 2 lanes
// = 2-way = free [m136].
__global__ void __launch_bounds__(256, 4)
kan_gemm(const unsigned short* __restrict__ Xb,
         const unsigned short* __restrict__ Cb,
         const int* __restrict__ seg_rows,
         const int* __restrict__ bucket_cnt,
         const float2* __restrict__ ws_s,
         const float* __restrict__ bias,
         float* __restrict__ out) {
  // XCD swizzle: sub&7 -> m-tile class (same XCD), sub>>3 -> n-tile (0..15).
  const int sub = blockIdx.x & 127;
  const int mt  = (blockIdx.x >> 7) * 8 + (sub & 7);
  const int nt  = sub >> 3;

  // Map m-tile -> (segment, local tile, bucket count) from the 9 counters.
  int seg = -1, lt = 0, cnt = 0;
  {
    int t0 = 0;
#pragma unroll
    for (int g = 0; g < NGRID; g++) {
      int c   = bucket_cnt[g];
      int ntg = (c + 127) >> 7;
      if (mt >= t0 && mt < t0 + ntg) { seg = g; lt = mt - t0; cnt = c; }
      t0 += ntg;
    }
  }
  if (seg < 0) return;                      // uniform over block: barrier-safe
  const int rlim = cnt - lt * 128;          // valid rows in this tile (1..128)
  const int* rows = seg_rows + seg * B_ROWS + lt * 128;

  __shared__ unsigned short As [128 * 64];   // 16 KB, rows of 64 shorts (BK=64)
  __shared__ unsigned short Bs0[ 64 * 64];   // 8 KB
  __shared__ unsigned short Bs1[ 64 * 64];   // 8 KB

  const int tid  = threadIdx.x;
  const int lane = tid & 63;
  const int wave = tid >> 6;                // 4 waves, 2x2 over 128x64
  const int wm   = wave >> 1;               // 0..1 -> 64-row half
  const int wn   = wave & 1;                // 0..1 -> 32-col half
  const int colB0 = nt * 64;

  // ---- staging geometry: one issue = 8 rows x 128B (full BK=64 row slice) --
  const int srow = lane >> 3;               // 0..7 row within issue
  const int sOff = ((lane & 7) ^ srow) * 8; // swizzled src chunk (shorts)

  // A: 16 issues of 8 rows -> 4 per wave. Clamp padding lanes (masked later).
  const unsigned short* gA[4];
#pragma unroll
  for (int i = 0; i < 4; i++) {
    int idx = (wave * 4 + i) * 8 + srow;
    int rid = rows[idx < rlim ? idx : rlim - 1];
    gA[i] = Xb + (size_t)rid * IDIM + sOff;
  }
  // B: 8 issues of 8 rows per plane -> 2 per wave per plane.
  const unsigned short* gB0[2];
  const unsigned short* gB1[2];
#pragma unroll
  for (int i = 0; i < 2; i++) {
    int rr = wave * 16 + i * 8 + srow;
    gB0[i] = Cb + ((size_t)(seg * ODIM + colB0 + rr)) * IDIM + sOff;
    gB1[i] = gB0[i] + (size_t)ODIM * IDIM;
  }

  // ---- reader geometry: row r=lane&15, logical chunk d = h*4 + (lane>>4),
  //      stored slot = d ^ (lane&7)  (r&7 == lane&7 since row bases %16==0) --
  const int rsw0 = ((((lane >> 4) & 3) | 0) ^ (lane & 7)) * 8;   // h=0
  const int rsw1 = ((((lane >> 4) & 3) | 4) ^ (lane & 7)) * 8;   // h=1

  f32x4 acc0[4][2] = {};
  f32x4 acc1[4][2] = {};

  for (int kk = 0; kk < IDIM; kk += 64) {
    __syncthreads();                        // prior iter's LDS reads complete
#pragma unroll
    for (int i = 0; i < 4; i++)
      async_cp16(gA[i] + kk, &As[(wave * 4 + i) * 512]);
#pragma unroll
    for (int i = 0; i < 2; i++) {
      async_cp16(gB0[i] + kk, &Bs0[(wave * 2 + i) * 512]);
      async_cp16(gB1[i] + kk, &Bs1[(wave * 2 + i) * 512]);
    }
    __syncthreads();                        // staging visible (vmcnt drain at barrier)

#pragma unroll
    for (int h = 0; h < 2; h++) {
      const int rs = h ? rsw1 : rsw0;
      frag8 af[4], bfr[2];
#pragma unroll
      for (int mi = 0; mi < 4; mi++)
        af[mi] = *(const frag8*)&As[(wm * 64 + mi * 16 + (lane & 15)) * 64 + rs];
#pragma unroll
      for (int ni = 0; ni < 2; ni++)
        bfr[ni] = *(const frag8*)&Bs0[((wn * 2 + ni) * 16 + (lane & 15)) * 64 + rs];
#pragma unroll
      for (int mi = 0; mi < 4; mi++)
#pragma unroll
        for (int ni = 0; ni < 2; ni++)
          acc0[mi][ni] = __builtin_amdgcn_mfma_f32_16x16x32_bf16(af[mi], bfr[ni], acc0[mi][ni], 0, 0, 0);
#pragma unroll
      for (int ni = 0; ni < 2; ni++)
        bfr[ni] = *(const frag8*)&Bs1[((wn * 2 + ni) * 16 + (lane & 15)) * 64 + rs];
#pragma unroll
      for (int mi = 0; mi < 4; mi++)
#pragma unroll
        for (int ni = 0; ni < 2; ni++)
          acc1[mi][ni] = __builtin_amdgcn_mfma_f32_16x16x32_bf16(af[mi], bfr[ni], acc1[mi][ni], 0, 0, 0);
    }
  }

  // Epilogue: D col = lane&15, row = (lane>>4)*4 + reg  [m89/m91 verified]
  // Weights read from the segment-sorted ws_s (contiguous), not via row id.
  const float2* wss = ws_s + seg * B_ROWS + lt * 128;
  int   col[2]; float bv[2];
#pragma unroll
  for (int ni = 0; ni < 2; ni++) {
    col[ni] = colB0 + wn * 32 + ni * 16 + (lane & 15);
    bv[ni]  = bias[col[ni]];
  }
#pragma unroll
  for (int mi = 0; mi < 4; mi++) {
    int irow = wm * 64 + mi * 16 + (lane >> 4) * 4;
#pragma unroll
    for (int r = 0; r < 4; r++) {
      int idx = irow + r;
      if (idx < rlim) {                     // non-padding row
        int orow = rows[idx];
        float2 w = wss[idx];
        float* o = out + (size_t)orow * ODIM;
#pragma unroll
        for (int ni = 0; ni < 2; ni++)
          o[col[ni]] = w.x * acc0[mi][ni][r] + w.y * acc1[mi][ni][r] + bv[ni];
      }
    }
  }
}

// ---------------- Fallback (ws too small): slow fp32, correct ----------------
__global__ void fallback_kernel(const float* __restrict__ x, const float* __restrict__ coeff,
                                const float* __restrict__ bias, float* __restrict__ out) {
  int b = blockIdx.x;
  int tid = threadIdx.x;
  __shared__ float xs[IDIM];
  __shared__ float ps[4];
  __shared__ float mw[2];
  __shared__ int   ms;
  float4 v = ((const float4*)(x + (size_t)b * IDIM))[tid];
  ((float4*)xs)[tid] = v;
  float s = v.x + v.y + v.z + v.w;
#pragma unroll
  for (int off = 32; off; off >>= 1) s += __shfl_down(s, off, 64);
  if ((tid & 63) == 0) ps[tid >> 6] = s;
  __syncthreads();
  if (tid == 0) {
    float m = (ps[0] + ps[1] + ps[2] + ps[3]) * (1.0f / (float)IDIM);
    int sI; float w0, w1;
    seg_weights(m, sI, w0, w1);
    mw[0] = w0; mw[1] = w1; ms = sI;
  }
  __syncthreads();
  float w0 = mw[0], w1 = mw[1]; int sI = ms;
  for (int o = tid; o < ODIM; o += 256) {
    const float* c0 = coeff + ((size_t)sI * ODIM + o) * IDIM;
    const float* c1 = c0 + (size_t)ODIM * IDIM;
    float a0 = 0.f, a1 = 0.f;
    for (int i = 0; i < IDIM; i++) { a0 += xs[i] * c0[i]; a1 += xs[i] * c1[i]; }
    out[(size_t)b * ODIM + o] = w0 * a0 + w1 * a1 + bias[o];
  }
}

extern "C" void kernel_launch(void* const* d_in, const int* in_sizes, int n_in,
                              void* d_out, int out_size, void* d_ws, size_t ws_size,
                              hipStream_t stream) {
  const float* x     = (const float*)d_in[0];
  const float* coeff = (const float*)d_in[1];
  const float* bias  = (const float*)d_in[2];
  float* out = (float*)d_out;

  // Workspace layout (16B-aligned chunks)
  size_t szXb = (size_t)B_ROWS * IDIM * sizeof(unsigned short);       // 33,554,432
  size_t szCb = (size_t)NGRID * ODIM * IDIM * sizeof(unsigned short); // 18,874,368
  size_t o0 = 0;
  unsigned short* Xb = (unsigned short*)((char*)d_ws + o0); o0 += szXb;
  unsigned short* Cb = (unsigned short*)((char*)d_ws + o0); o0 += szCb;
  float2* ws_s = (float2*)((char*)d_ws + o0); o0 += (size_t)NGRID * B_ROWS * 8;
  int* seg_rows = (int*)((char*)d_ws + o0); o0 += (size_t)NGRID * B_ROWS * 4;
  int* bucket_cnt = (int*)((char*)d_ws + o0); o0 += 256;

  if (ws_size < o0) {
    // Emergency slow path: no workspace required.
    fallback_kernel<<<B_ROWS, 256, 0, stream>>>(x, coeff, bias, out);
    return;
  }

  hipMemsetAsync(bucket_cnt, 0, NGRID * sizeof(int), stream);
  row_stats_fused<<<RS_BLOCKS, 256, 0, stream>>>(x, Xb, ws_s, seg_rows, bucket_cnt);
  cvt_coeff<<<NGRID * CV_BLKS_PER_PLANE, 256, 0, stream>>>(coeff, Cb, bucket_cnt);
  kan_gemm<<<GEMM_BLOCKS, 256, 0, stream>>>(Xb, Cb, seg_rows, bucket_cnt, ws_s, bias, out);
}

// Round 6
// 226.164 us; speedup vs baseline: 1.3308x; 1.0388x over previous
//
#include <hip/hip_runtime.h>
#include <math.h>

// Problem constants
#define B_ROWS 16384      // 8*2048 batch rows
#define IDIM   1024
#define ODIM   1024
#define NGRID  9          // NUM_SEGMENTS + 1

#define RS_BLOCKS 1024
#define RS_ROWS   (B_ROWS / RS_BLOCKS)   // 16 rows per block

// GEMM grid: BM=128 BN=64 -> 16 n-tiles. 18 groups x 128 = 2304 blocks.
// Swizzle: within a 128-id window, (id&7) selects m-tile class -> the 16
// n-blocks of one m-tile share an XCD (round-robin dispatch) for A-tile L2 reuse.
#define GEMM_GROUPS 18
#define GEMM_BLOCKS (GEMM_GROUPS * 128)

typedef __attribute__((ext_vector_type(8))) short frag8;   // 8 x bf16 (4 VGPRs)
typedef __attribute__((ext_vector_type(4))) float f32x4;   // MFMA accumulator

typedef __attribute__((address_space(1))) void gvoid;
typedef __attribute__((address_space(3))) void lvoid;

__device__ __forceinline__ void async_cp16(const void* g, void* l) {
  // 16B/lane global->LDS DMA; LDS dest = wave-uniform base + lane*16.
  // Global side is a normal per-lane VMEM address (gather OK).
  __builtin_amdgcn_global_load_lds((gvoid*)(void*)g, (lvoid*)l, 16, 0, 0);
}

__device__ __forceinline__ unsigned short f2bf(float f) {
  union { float f; unsigned u; } v; v.f = f;
  unsigned u = v.u;
  u += 0x7fffu + ((u >> 16) & 1u);      // round-to-nearest-even
  return (unsigned short)(u >> 16);
}

// Per-row hat weights: at most 2 nonzero, at segments {s, s+1}
__device__ __forceinline__ void seg_weights(float m, int& sI, float& w0, float& w1) {
  float wsum = 0.f, wg[NGRID];
#pragma unroll
  for (int g = 0; g < NGRID; g++) {
    float gv = -1.f + 0.25f * (float)g;
    float t = 1.f - fabsf(m - gv) * 4.f;   // 1/h = 4
    wg[g] = t > 0.f ? t : 0.f;
    wsum += wg[g];
  }
  int s = (int)floorf((m + 1.f) * 4.f);
  s = s < 0 ? 0 : (s > 7 ? 7 : s);
  float inv = 1.f / (wsum + 1e-8f);
  sI = s;
  w0 = wg[s] * inv;
  w1 = wg[s + 1] * inv;
}

// ---------------- Pass 1 (fused): mean/weights/segment + bf16 cvt + seg lists --
// Each wave handles one row: data stays in registers, so the bf16 copy is
// written with NO re-read. Two-level atomic aggregation for ranks.
// Weights are ALSO stored segment-sorted (ws_s[seg*B_ROWS + rank]) so the
// GEMM epilogue reads them contiguously instead of scattering via row id.
__global__ void row_stats_fused(const float* __restrict__ x,
                                unsigned short* __restrict__ Xb,
                                float2* __restrict__ ws_s,
                                int* __restrict__ seg_rows,
                                int* __restrict__ bucket_cnt) {
  __shared__ int lcnt[NGRID];
  __shared__ int base[NGRID];
  __shared__ int lrank[RS_ROWS];
  __shared__ int lseg[RS_ROWS];
  __shared__ float2 lws[RS_ROWS];
  const int tid  = threadIdx.x;          // 256 threads, 4 waves
  const int lane = tid & 63;
  const int wave = tid >> 6;
  if (tid < NGRID) lcnt[tid] = 0;
  __syncthreads();
  const int row0 = blockIdx.x * RS_ROWS;
#pragma unroll
  for (int it = 0; it < RS_ROWS / 4; ++it) {
    int r = it * 4 + wave;               // one wave per row
    int b = row0 + r;
    const float4* xr = (const float4*)(x + (size_t)b * IDIM);
    ushort4* xw = (ushort4*)(Xb + (size_t)b * IDIM);
    float4 v[4];
    float s = 0.f;
#pragma unroll
    for (int j = 0; j < 4; j++) {        // 4 independent 16B loads/lane
      v[j] = xr[lane + j * 64];
      s += v[j].x + v[j].y + v[j].z + v[j].w;
    }
#pragma unroll
    for (int j = 0; j < 4; j++) {        // bf16 copy straight from registers
      ushort4 u;
      u.x = f2bf(v[j].x); u.y = f2bf(v[j].y); u.z = f2bf(v[j].z); u.w = f2bf(v[j].w);
      xw[lane + j * 64] = u;
    }
#pragma unroll
    for (int off = 32; off; off >>= 1) s += __shfl_down(s, off, 64);
    if (lane == 0) {
      float m = s * (1.0f / (float)IDIM);
      int sI; float w0, w1;
      seg_weights(m, sI, w0, w1);
      lws[r] = make_float2(w0, w1);
      lseg[r] = sI;
      lrank[r] = atomicAdd(&lcnt[sI], 1);   // LDS atomic: cheap
    }
  }
  __syncthreads();
  if (tid < NGRID) base[tid] = lcnt[tid] ? atomicAdd(&bucket_cnt[tid], lcnt[tid]) : 0;
  __syncthreads();
  if (tid < RS_ROWS) {
    int p = lseg[tid] * B_ROWS + base[lseg[tid]] + lrank[tid];
    seg_rows[p] = row0 + tid;
    ws_s[p] = lws[tid];
  }
}

// ---------------- Pass 2: coeff fp32 -> bf16, only planes actually needed ----
// Plane h is needed iff some non-empty bucket g has h in {g, g+1}.
#define CV_BLKS_PER_PLANE (ODIM * IDIM / 4 / 256)   // 1024
__global__ void cvt_coeff(const float* __restrict__ c, unsigned short* __restrict__ cb,
                          const int* __restrict__ bucket_cnt) {
  const int g  = blockIdx.x >> 10;            // plane 0..8
  const int cI = blockIdx.x & 1023;
  bool need = bucket_cnt[g] > 0;
  if (!need && g > 0) need = bucket_cnt[g - 1] > 0;
  if (!need) return;
  int i = (g * CV_BLKS_PER_PLANE + cI) * 256 + threadIdx.x;
  float4 v = ((const float4*)c)[i];
  ushort4 o;
  o.x = f2bf(v.x); o.y = f2bf(v.y); o.z = f2bf(v.z); o.w = f2bf(v.w);
  ((ushort4*)cb)[i] = o;
}

// ---------------- Pass 3: MFMA GEMM, dual-acc, BM=128 BN=64, gather-A --------
// acc0 = X[rows] @ coeff[seg]^T, acc1 = X[rows] @ coeff[seg+1]^T  (K=1024)
// out[row] = w0*acc0 + w1*acc1 + bias.  Round-0 proven schedule (single-buffer
// 2-barrier), 128B-granule staging (R5: FETCH 85->68MB, 0 conflicts), plus:
// PHASE-STAGGERED K-LOOP. Accumulation over K is commutative, so block b
// starts its K-sweep at iteration s_b = ((blockIdx.x>>8)*5)&15 and wraps.
// Co-resident blocks on a CU (ids differing by ~256) get different phase
// offsets -> one block's staging-barrier drain overlaps another block's MFMA
// phase instead of convoying. Blocks within one swizzle window (same >>8)
// keep identical stagger, preserving the shared-A-tile L2 locality.
__global__ void __launch_bounds__(256, 4)
kan_gemm(const unsigned short* __restrict__ Xb,
         const unsigned short* __restrict__ Cb,
         const int* __restrict__ seg_rows,
         const int* __restrict__ bucket_cnt,
         const float2* __restrict__ ws_s,
         const float* __restrict__ bias,
         float* __restrict__ out) {
  // XCD swizzle: sub&7 -> m-tile class (same XCD), sub>>3 -> n-tile (0..15).
  const int sub = blockIdx.x & 127;
  const int mt  = (blockIdx.x >> 7) * 8 + (sub & 7);
  const int nt  = sub >> 3;

  // Map m-tile -> (segment, local tile, bucket count) from the 9 counters.
  int seg = -1, lt = 0, cnt = 0;
  {
    int t0 = 0;
#pragma unroll
    for (int g = 0; g < NGRID; g++) {
      int c   = bucket_cnt[g];
      int ntg = (c + 127) >> 7;
      if (mt >= t0 && mt < t0 + ntg) { seg = g; lt = mt - t0; cnt = c; }
      t0 += ntg;
    }
  }
  if (seg < 0) return;                      // uniform over block: barrier-safe
  const int rlim = cnt - lt * 128;          // valid rows in this tile (1..128)
  const int* rows = seg_rows + seg * B_ROWS + lt * 128;

  __shared__ unsigned short As [128 * 64];   // 16 KB, rows of 64 shorts (BK=64)
  __shared__ unsigned short Bs0[ 64 * 64];   // 8 KB
  __shared__ unsigned short Bs1[ 64 * 64];   // 8 KB

  const int tid  = threadIdx.x;
  const int lane = tid & 63;
  const int wave = tid >> 6;                // 4 waves, 2x2 over 128x64
  const int wm   = wave >> 1;               // 0..1 -> 64-row half
  const int wn   = wave & 1;                // 0..1 -> 32-col half
  const int colB0 = nt * 64;

  // ---- staging geometry: one issue = 8 rows x 128B (full BK=64 row slice) --
  const int srow = lane >> 3;               // 0..7 row within issue
  const int sOff = ((lane & 7) ^ srow) * 8; // swizzled src chunk (shorts)

  // A: 16 issues of 8 rows -> 4 per wave. Clamp padding lanes (masked later).
  const unsigned short* gA[4];
#pragma unroll
  for (int i = 0; i < 4; i++) {
    int idx = (wave * 4 + i) * 8 + srow;
    int rid = rows[idx < rlim ? idx : rlim - 1];
    gA[i] = Xb + (size_t)rid * IDIM + sOff;
  }
  // B: 8 issues of 8 rows per plane -> 2 per wave per plane.
  const unsigned short* gB0[2];
  const unsigned short* gB1[2];
#pragma unroll
  for (int i = 0; i < 2; i++) {
    int rr = wave * 16 + i * 8 + srow;
    gB0[i] = Cb + ((size_t)(seg * ODIM + colB0 + rr)) * IDIM + sOff;
    gB1[i] = gB0[i] + (size_t)ODIM * IDIM;
  }

  // ---- reader geometry: row r=lane&15, logical chunk d = h*4 + (lane>>4),
  //      stored slot = d ^ (lane&7)  (r&7 == lane&7 since row bases %16==0) --
  const int rsw0 = ((((lane >> 4) & 3) | 0) ^ (lane & 7)) * 8;   // h=0
  const int rsw1 = ((((lane >> 4) & 3) | 4) ^ (lane & 7)) * 8;   // h=1

  f32x4 acc0[4][2] = {};
  f32x4 acc1[4][2] = {};

  // Phase stagger: co-resident blocks start at different K-iterations.
  const int kstart = ((blockIdx.x >> 8) * 5) & 15;

  for (int it = 0; it < 16; ++it) {
    const int kk = (((it + kstart) & 15) << 6);   // staggered K offset
    __syncthreads();                        // prior iter's LDS reads complete
#pragma unroll
    for (int i = 0; i < 4; i++)
      async_cp16(gA[i] + kk, &As[(wave * 4 + i) * 512]);
#pragma unroll
    for (int i = 0; i < 2; i++) {
      async_cp16(gB0[i] + kk, &Bs0[(wave * 2 + i) * 512]);
      async_cp16(gB1[i] + kk, &Bs1[(wave * 2 + i) * 512]);
    }
    __syncthreads();                        // staging visible (vmcnt drain at barrier)

#pragma unroll
    for (int h = 0; h < 2; h++) {
      const int rs = h ? rsw1 : rsw0;
      frag8 af[4], bfr[2];
#pragma unroll
      for (int mi = 0; mi < 4; mi++)
        af[mi] = *(const frag8*)&As[(wm * 64 + mi * 16 + (lane & 15)) * 64 + rs];
#pragma unroll
      for (int ni = 0; ni < 2; ni++)
        bfr[ni] = *(const frag8*)&Bs0[((wn * 2 + ni) * 16 + (lane & 15)) * 64 + rs];
#pragma unroll
      for (int mi = 0; mi < 4; mi++)
#pragma unroll
        for (int ni = 0; ni < 2; ni++)
          acc0[mi][ni] = __builtin_amdgcn_mfma_f32_16x16x32_bf16(af[mi], bfr[ni], acc0[mi][ni], 0, 0, 0);
#pragma unroll
      for (int ni = 0; ni < 2; ni++)
        bfr[ni] = *(const frag8*)&Bs1[((wn * 2 + ni) * 16 + (lane & 15)) * 64 + rs];
#pragma unroll
      for (int mi = 0; mi < 4; mi++)
#pragma unroll
        for (int ni = 0; ni < 2; ni++)
          acc1[mi][ni] = __builtin_amdgcn_mfma_f32_16x16x32_bf16(af[mi], bfr[ni], acc1[mi][ni], 0, 0, 0);
    }
  }

  // Epilogue: D col = lane&15, row = (lane>>4)*4 + reg  [m89/m91 verified]
  // Weights read from the segment-sorted ws_s (contiguous), not via row id.
  const float2* wss = ws_s + seg * B_ROWS + lt * 128;
  int   col[2]; float bv[2];
#pragma unroll
  for (int ni = 0; ni < 2; ni++) {
    col[ni] = colB0 + wn * 32 + ni * 16 + (lane & 15);
    bv[ni]  = bias[col[ni]];
  }
#pragma unroll
  for (int mi = 0; mi < 4; mi++) {
    int irow = wm * 64 + mi * 16 + (lane >> 4) * 4;
#pragma unroll
    for (int r = 0; r < 4; r++) {
      int idx = irow + r;
      if (idx < rlim) {                     // non-padding row
        int orow = rows[idx];
        float2 w = wss[idx];
        float* o = out + (size_t)orow * ODIM;
#pragma unroll
        for (int ni = 0; ni < 2; ni++)
          o[col[ni]] = w.x * acc0[mi][ni][r] + w.y * acc1[mi][ni][r] + bv[ni];
      }
    }
  }
}

// ---------------- Fallback (ws too small): slow fp32, correct ----------------
__global__ void fallback_kernel(const float* __restrict__ x, const float* __restrict__ coeff,
                                const float* __restrict__ bias, float* __restrict__ out) {
  int b = blockIdx.x;
  int tid = threadIdx.x;
  __shared__ float xs[IDIM];
  __shared__ float ps[4];
  __shared__ float mw[2];
  __shared__ int   ms;
  float4 v = ((const float4*)(x + (size_t)b * IDIM))[tid];
  ((float4*)xs)[tid] = v;
  float s = v.x + v.y + v.z + v.w;
#pragma unroll
  for (int off = 32; off; off >>= 1) s += __shfl_down(s, off, 64);
  if ((tid & 63) == 0) ps[tid >> 6] = s;
  __syncthreads();
  if (tid == 0) {
    float m = (ps[0] + ps[1] + ps[2] + ps[3]) * (1.0f / (float)IDIM);
    int sI; float w0, w1;
    seg_weights(m, sI, w0, w1);
    mw[0] = w0; mw[1] = w1; ms = sI;
  }
  __syncthreads();
  float w0 = mw[0], w1 = mw[1]; int sI = ms;
  for (int o = tid; o < ODIM; o += 256) {
    const float* c0 = coeff + ((size_t)sI * ODIM + o) * IDIM;
    const float* c1 = c0 + (size_t)ODIM * IDIM;
    float a0 = 0.f, a1 = 0.f;
    for (int i = 0; i < IDIM; i++) { a0 += xs[i] * c0[i]; a1 += xs[i] * c1[i]; }
    out[(size_t)b * ODIM + o] = w0 * a0 + w1 * a1 + bias[o];
  }
}

extern "C" void kernel_launch(void* const* d_in, const int* in_sizes, int n_in,
                              void* d_out, int out_size, void* d_ws, size_t ws_size,
                              hipStream_t stream) {
  const float* x     = (const float*)d_in[0];
  const float* coeff = (const float*)d_in[1];
  const float* bias  = (const float*)d_in[2];
  float* out = (float*)d_out;

  // Workspace layout (16B-aligned chunks)
  size_t szXb = (size_t)B_ROWS * IDIM * sizeof(unsigned short);       // 33,554,432
  size_t szCb = (size_t)NGRID * ODIM * IDIM * sizeof(unsigned short); // 18,874,368
  size_t o0 = 0;
  unsigned short* Xb = (unsigned short*)((char*)d_ws + o0); o0 += szXb;
  unsigned short* Cb = (unsigned short*)((char*)d_ws + o0); o0 += szCb;
  float2* ws_s = (float2*)((char*)d_ws + o0); o0 += (size_t)NGRID * B_ROWS * 8;
  int* seg_rows = (int*)((char*)d_ws + o0); o0 += (size_t)NGRID * B_ROWS * 4;
  int* bucket_cnt = (int*)((char*)d_ws + o0); o0 += 256;

  if (ws_size < o0) {
    // Emergency slow path: no workspace required.
    fallback_kernel<<<B_ROWS, 256, 0, stream>>>(x, coeff, bias, out);
    return;
  }

  hipMemsetAsync(bucket_cnt, 0, NGRID * sizeof(int), stream);
  row_stats_fused<<<RS_BLOCKS, 256, 0, stream>>>(x, Xb, ws_s, seg_rows, bucket_cnt);
  cvt_coeff<<<NGRID * CV_BLKS_PER_PLANE, 256, 0, stream>>>(coeff, Cb, bucket_cnt);
  kan_gemm<<<GEMM_BLOCKS, 256, 0, stream>>>(Xb, Cb, seg_rows, bucket_cnt, ws_s, bias, out);
}